// Round 1
// baseline (1716.497 us; speedup 1.0000x reference)
//
#include <hip/hip_runtime.h>

namespace {

constexpr int Bn = 8192;
constexpr int Tn = 365;
constexpr int In = 3;
constexpr int Hn = 34;
constexpr int G4 = 4 * Hn;   // 136 gate rows (i,f,g,o blocks of 34)
constexpr int BB = 32;       // batches per block
constexpr int HP = 36;       // padded row length (16B-aligned rows for b128 LDS reads)

__device__ __forceinline__ float sigf(float v) { return 1.f / (1.f + __expf(-v)); }
// tanh(x) = 1 - 2/(e^{2x}+1): saturates correctly to +-1 for large |x| (no inf-inf NaN)
__device__ __forceinline__ float tanhfast(float v) { return 1.f - 2.f / (__expf(2.f * v) + 1.f); }

__global__ __launch_bounds__(256) void lstm_kernel(
    const float* __restrict__ x,      // [B,T,3]
    const float* __restrict__ fc0_w,  // [34,3]
    const float* __restrict__ fc0_b,  // [34]
    const float* __restrict__ w_ih,   // [136,34]
    const float* __restrict__ w_hh,   // [136,34]
    const float* __restrict__ b_ih,   // [136]
    const float* __restrict__ b_hh,   // [136]
    float* __restrict__ out)          // [B,T,34]
{
    __shared__ float w_lds[G4][HP];    // w_hh rows, padded
    __shared__ float wc_lds[G4][4];    // folded input weights Wc = w_ih @ fc0_w  (3 used)
    __shared__ float bc_lds[G4];       // folded bias = w_ih @ fc0_b + b_ih + b_hh
    __shared__ float h_lds[2][BB][HP]; // double-buffered hidden state

    const int tid = threadIdx.x;

    // --- stage w_hh into LDS ---
    for (int idx = tid; idx < G4 * Hn; idx += 256) {
        int r = idx / Hn, k = idx - r * Hn;
        w_lds[r][k] = w_hh[idx];
    }
    // --- fold fc0 into w_ih: Wc[136][3], bc[136] (cheap, redundant per block) ---
    for (int r = tid; r < G4; r += 256) {
        float a0 = 0.f, a1 = 0.f, a2 = 0.f, ab = 0.f;
        for (int k = 0; k < Hn; ++k) {
            float w = w_ih[r * Hn + k];
            a0 += w * fc0_w[k * 3 + 0];
            a1 += w * fc0_w[k * 3 + 1];
            a2 += w * fc0_w[k * 3 + 2];
            ab += w * fc0_b[k];
        }
        wc_lds[r][0] = a0; wc_lds[r][1] = a1; wc_lds[r][2] = a2; wc_lds[r][3] = 0.f;
        bc_lds[r] = ab + b_ih[r] + b_hh[r];
    }
    // --- zero h buffers ---
    for (int idx = tid; idx < 2 * BB * HP; idx += 256)
        ((float*)h_lds)[idx] = 0.f;
    __syncthreads();

    const int lane = tid & 63;
    const int wv   = tid >> 6;    // wave 0..3
    const int bl   = lane & 31;   // local batch
    const int half = lane >> 5;   // j-half: j = p + 17*half
    const long long bg = (long long)blockIdx.x * BB + bl;

    // 17 j-pairs distributed {5,4,4,4} across 4 waves
    const int pst[5] = {0, 5, 9, 13, 17};
    const int p0 = pst[wv];
    const int np = pst[wv + 1] - p0;

    float c[5] = {0.f, 0.f, 0.f, 0.f, 0.f};  // cell state, static-indexed

    const float* xb = x + bg * (long long)(Tn * In);
    float xc0 = xb[0], xc1 = xb[1], xc2 = xb[2];

    int cur = 0;
    for (int t = 0; t < Tn; ++t) {
        // prefetch next timestep's x (hide global latency under this step's compute)
        float xn0 = 0.f, xn1 = 0.f, xn2 = 0.f;
        if (t + 1 < Tn) {
            const float* xp = xb + (t + 1) * 3;
            xn0 = xp[0]; xn1 = xp[1]; xn2 = xp[2];
        }

        // load full h_old for this lane's batch into registers (b128-friendly)
        float hreg[Hn];
        #pragma unroll
        for (int k = 0; k < Hn; ++k) hreg[k] = h_lds[cur][bl][k];

        const int nxt = cur ^ 1;

        #pragma unroll
        for (int pi = 0; pi < 5; ++pi) {
            if (pi >= np) break;            // wave-uniform
            const int j = p0 + pi + 17 * half;
            // folded input-side gates: bc + Wc @ x
            float a0 = bc_lds[0 * Hn + j] + wc_lds[0 * Hn + j][0] * xc0 + wc_lds[0 * Hn + j][1] * xc1 + wc_lds[0 * Hn + j][2] * xc2;
            float a1 = bc_lds[1 * Hn + j] + wc_lds[1 * Hn + j][0] * xc0 + wc_lds[1 * Hn + j][1] * xc1 + wc_lds[1 * Hn + j][2] * xc2;
            float a2 = bc_lds[2 * Hn + j] + wc_lds[2 * Hn + j][0] * xc0 + wc_lds[2 * Hn + j][1] * xc1 + wc_lds[2 * Hn + j][2] * xc2;
            float a3 = bc_lds[3 * Hn + j] + wc_lds[3 * Hn + j][0] * xc0 + wc_lds[3 * Hn + j][1] * xc1 + wc_lds[3 * Hn + j][2] * xc2;
            // recurrent matvec: 4 independent accumulator chains (hides FMA latency)
            #pragma unroll
            for (int k = 0; k < Hn; ++k) {
                const float hk = hreg[k];
                a0 += w_lds[0 * Hn + j][k] * hk;
                a1 += w_lds[1 * Hn + j][k] * hk;
                a2 += w_lds[2 * Hn + j][k] * hk;
                a3 += w_lds[3 * Hn + j][k] * hk;
            }
            const float ig = sigf(a0);
            const float fg = sigf(a1);
            const float gg = tanhfast(a2);
            const float og = sigf(a3);
            const float cn = fg * c[pi] + ig * gg;
            c[pi] = cn;
            const float hn = og * tanhfast(cn);
            h_lds[nxt][bl][j] = hn;
        }
        __syncthreads();   // h_new complete; also fences prior-step out-reads

        // coalesced-ish output flush: 34 floats = 17 float2 per (b,t) row
        float* outb = out + (long long)blockIdx.x * BB * (Tn * Hn) + (long long)t * Hn;
        for (int idx = tid; idx < BB * 17; idx += 256) {
            int b = idx / 17;
            int cc = idx - b * 17;
            float2 v;
            v.x = h_lds[nxt][b][2 * cc];
            v.y = h_lds[nxt][b][2 * cc + 1];
            *(float2*)(outb + (long long)b * (Tn * Hn) + 2 * cc) = v;
        }

        cur = nxt;
        xc0 = xn0; xc1 = xn1; xc2 = xn2;
    }
}

} // namespace

extern "C" void kernel_launch(void* const* d_in, const int* in_sizes, int n_in,
                              void* d_out, int out_size, void* d_ws, size_t ws_size,
                              hipStream_t stream) {
    const float* x     = (const float*)d_in[0];
    const float* fc0_w = (const float*)d_in[1];
    const float* fc0_b = (const float*)d_in[2];
    const float* w_ih  = (const float*)d_in[3];
    const float* w_hh  = (const float*)d_in[4];
    const float* b_ih  = (const float*)d_in[5];
    const float* b_hh  = (const float*)d_in[6];
    float* out = (float*)d_out;

    lstm_kernel<<<Bn / BB, 256, 0, stream>>>(x, fc0_w, fc0_b, w_ih, w_hh, b_ih, b_hh, out);
}

// Round 2
// 1136.428 us; speedup vs baseline: 1.5104x; 1.5104x over previous
//
#include <hip/hip_runtime.h>

namespace {

constexpr int Bn = 8192;
constexpr int Tn = 365;
constexpr int In = 3;
constexpr int Hn = 34;
constexpr int G4 = 4 * Hn;   // 136 gate rows (i,f,g,o blocks of 34)
constexpr int BB = 16;       // batches per block (16 -> grid 512 -> 2 blocks/CU)
constexpr int HP = 36;       // padded row length (16B-aligned rows; 2-way banks at BB=16)

__device__ __forceinline__ float sigf(float v) { return 1.f / (1.f + __expf(-v)); }
// tanh(x) = 1 - 2/(e^{2x}+1): saturates correctly to +-1 for large |x|
__device__ __forceinline__ float tanhfast(float v) { return 1.f - 2.f / (__expf(2.f * v) + 1.f); }

// one LSTM cell column j: 4 gate dot-products against h, nonlinearity, c/h update
__device__ __forceinline__ void cell(
    int j,
    const float hreg[Hn],
    const float (*w_lds)[HP],
    const float (*wc_lds)[4],
    float x0, float x1, float x2,
    float& c, float* hout)
{
    const float* w0 = w_lds[0 * Hn + j];
    const float* w1 = w_lds[1 * Hn + j];
    const float* w2 = w_lds[2 * Hn + j];
    const float* w3 = w_lds[3 * Hn + j];
    const float4 q0 = *(const float4*)wc_lds[0 * Hn + j];
    const float4 q1 = *(const float4*)wc_lds[1 * Hn + j];
    const float4 q2 = *(const float4*)wc_lds[2 * Hn + j];
    const float4 q3 = *(const float4*)wc_lds[3 * Hn + j];
    float a0 = q0.w + q0.x * x0 + q0.y * x1 + q0.z * x2;
    float a1 = q1.w + q1.x * x0 + q1.y * x1 + q1.z * x2;
    float a2 = q2.w + q2.x * x0 + q2.y * x1 + q2.z * x2;
    float a3 = q3.w + q3.x * x0 + q3.y * x1 + q3.z * x2;
    #pragma unroll
    for (int k = 0; k < Hn; ++k) {
        const float hk = hreg[k];
        a0 += w0[k] * hk;
        a1 += w1[k] * hk;
        a2 += w2[k] * hk;
        a3 += w3[k] * hk;
    }
    const float ig = sigf(a0);
    const float fg = sigf(a1);
    const float gg = tanhfast(a2);
    const float og = sigf(a3);
    c = fg * c + ig * gg;
    *hout = og * tanhfast(c);
}

__global__ __launch_bounds__(256) void lstm_kernel(
    const float* __restrict__ x,      // [B,T,3]
    const float* __restrict__ fc0_w,  // [34,3]
    const float* __restrict__ fc0_b,  // [34]
    const float* __restrict__ w_ih,   // [136,34]
    const float* __restrict__ w_hh,   // [136,34]
    const float* __restrict__ b_ih,   // [136]
    const float* __restrict__ b_hh,   // [136]
    float* __restrict__ out)          // [B,T,34]
{
    __shared__ float w_lds[G4][HP];    // w_hh rows, padded
    __shared__ float wc_lds[G4][4];    // xyz = folded Wc = w_ih@fc0_w, w = folded bias
    __shared__ float h_lds[2][BB][HP]; // double-buffered hidden state

    const int tid = threadIdx.x;

    // --- stage w_hh into LDS ---
    for (int idx = tid; idx < G4 * Hn; idx += 256) {
        int r = idx / Hn, k = idx - r * Hn;
        w_lds[r][k] = w_hh[idx];
    }
    // --- fold fc0 into w_ih: Wc[136][3] + bias (cheap, once per block) ---
    for (int r = tid; r < G4; r += 256) {
        float a0 = 0.f, a1 = 0.f, a2 = 0.f, ab = 0.f;
        for (int k = 0; k < Hn; ++k) {
            float w = w_ih[r * Hn + k];
            a0 += w * fc0_w[k * 3 + 0];
            a1 += w * fc0_w[k * 3 + 1];
            a2 += w * fc0_w[k * 3 + 2];
            ab += w * fc0_b[k];
        }
        wc_lds[r][0] = a0; wc_lds[r][1] = a1; wc_lds[r][2] = a2;
        wc_lds[r][3] = ab + b_ih[r] + b_hh[r];
    }
    // --- zero h buffers ---
    for (int idx = tid; idx < 2 * BB * HP; idx += 256)
        ((float*)h_lds)[idx] = 0.f;
    __syncthreads();

    const int lane = tid & 63;
    const int wv   = tid >> 6;     // wave 0..3
    const int bl   = lane & 15;    // local batch 0..15
    const int sub  = lane >> 4;    // sub-slot 0..3
    const int slot = sub * 4 + wv; // 0..15; slots 0,1 (extra-j) land in waves 0,1
    const long long bg = (long long)blockIdx.x * BB + bl;

    const int j0 = slot;           // 0..15
    const int j1 = slot + 16;      // 16..31
    const int j2 = slot + 32;      // 32,33 valid only for slot<2
    const bool has2 = (slot < 2);

    float c0 = 0.f, c1 = 0.f, c2 = 0.f;

    const float* xb = x + bg * (long long)(Tn * In);
    float x0 = xb[0], x1 = xb[1], x2 = xb[2];

    int cur = 0;
    for (int t = 0; t < Tn; ++t) {
        // prefetch next timestep's x under this step's compute
        float xn0 = 0.f, xn1 = 0.f, xn2 = 0.f;
        if (t + 1 < Tn) {
            const float* xp = xb + (t + 1) * 3;
            xn0 = xp[0]; xn1 = xp[1]; xn2 = xp[2];
        }

        // h_old for this lane's batch -> registers (b128 reads, 2-way banks = free)
        float hreg[Hn];
        #pragma unroll
        for (int k = 0; k < Hn; ++k) hreg[k] = h_lds[cur][bl][k];

        const int nxt = cur ^ 1;

        cell(j0, hreg, w_lds, wc_lds, x0, x1, x2, c0, &h_lds[nxt][bl][j0]);
        cell(j1, hreg, w_lds, wc_lds, x0, x1, x2, c1, &h_lds[nxt][bl][j1]);
        if (has2)
            cell(j2, hreg, w_lds, wc_lds, x0, x1, x2, c2, &h_lds[nxt][bl][j2]);

        __syncthreads();   // h_new complete

        // output flush: 16 batches x 34 floats = 272 float2 halves -> 2 passes
        float* outb = out + (long long)blockIdx.x * BB * (Tn * Hn) + (long long)t * Hn;
        #pragma unroll
        for (int pass = 0; pass < 2; ++pass) {
            int idx = tid + pass * 256;
            if (idx < BB * 17) {
                int b = idx / 17;
                int cc = idx - b * 17;
                float2 v;
                v.x = h_lds[nxt][b][2 * cc];
                v.y = h_lds[nxt][b][2 * cc + 1];
                *(float2*)(outb + (long long)b * (Tn * Hn) + 2 * cc) = v;
            }
        }

        cur = nxt;
        x0 = xn0; x1 = xn1; x2 = xn2;
    }
}

} // namespace

extern "C" void kernel_launch(void* const* d_in, const int* in_sizes, int n_in,
                              void* d_out, int out_size, void* d_ws, size_t ws_size,
                              hipStream_t stream) {
    const float* x     = (const float*)d_in[0];
    const float* fc0_w = (const float*)d_in[1];
    const float* fc0_b = (const float*)d_in[2];
    const float* w_ih  = (const float*)d_in[3];
    const float* w_hh  = (const float*)d_in[4];
    const float* b_ih  = (const float*)d_in[5];
    const float* b_hh  = (const float*)d_in[6];
    float* out = (float*)d_out;

    lstm_kernel<<<Bn / BB, 256, 0, stream>>>(x, fc0_w, fc0_b, w_ih, w_hh, b_ih, b_hh, out);
}

// Round 3
// 1124.024 us; speedup vs baseline: 1.5271x; 1.0110x over previous
//
#include <hip/hip_runtime.h>

namespace {

constexpr int Bn = 8192;
constexpr int Tn = 365;
constexpr int In = 3;
constexpr int Hn = 34;
constexpr int G4 = 4 * Hn;   // 136 gate rows (i,f,g,o blocks of 34)
constexpr int BB = 8;        // batches per block -> grid 1024 -> 4 blocks/CU
constexpr int HP = 36;       // padded row length (16B-aligned rows)

__device__ __forceinline__ float sigf(float v) { return 1.f / (1.f + __expf(-v)); }
// tanh(x) = 1 - 2/(e^{2x}+1): saturates correctly to +-1 for large |x|
__device__ __forceinline__ float tanhfast(float v) { return 1.f - 2.f / (__expf(2.f * v) + 1.f); }

// one LSTM cell column j: 4 gate dot-products vs h, nonlinearity, c update; returns h
__device__ __forceinline__ float cellc(
    int j,
    const float* __restrict__ hreg,
    const float (*__restrict__ w_lds)[HP],
    float4 q0, float4 q1, float4 q2, float4 q3,
    float x0, float x1, float x2,
    float& c)
{
    const float* w0 = w_lds[0 * Hn + j];
    const float* w1 = w_lds[1 * Hn + j];
    const float* w2 = w_lds[2 * Hn + j];
    const float* w3 = w_lds[3 * Hn + j];
    float a0 = q0.w + q0.x * x0 + q0.y * x1 + q0.z * x2;
    float a1 = q1.w + q1.x * x0 + q1.y * x1 + q1.z * x2;
    float a2 = q2.w + q2.x * x0 + q2.y * x1 + q2.z * x2;
    float a3 = q3.w + q3.x * x0 + q3.y * x1 + q3.z * x2;
    #pragma unroll
    for (int k = 0; k < Hn; ++k) {
        const float hk = hreg[k];
        a0 += w0[k] * hk;
        a1 += w1[k] * hk;
        a2 += w2[k] * hk;
        a3 += w3[k] * hk;
    }
    const float ig = sigf(a0);
    const float fg = sigf(a1);
    const float gg = tanhfast(a2);
    const float og = sigf(a3);
    c = fg * c + ig * gg;
    return og * tanhfast(c);
}

__global__ __launch_bounds__(256) void lstm_kernel(
    const float* __restrict__ x,      // [B,T,3]
    const float* __restrict__ fc0_w,  // [34,3]
    const float* __restrict__ fc0_b,  // [34]
    const float* __restrict__ w_ih,   // [136,34]
    const float* __restrict__ w_hh,   // [136,34]
    const float* __restrict__ b_ih,   // [136]
    const float* __restrict__ b_hh,   // [136]
    float* __restrict__ out)          // [B,T,34]
{
    __shared__ float w_lds[G4][HP];    // w_hh rows, padded
    __shared__ float wc_lds[G4][4];    // xyz = folded Wc = w_ih@fc0_w, w = folded bias
    __shared__ float h_lds[2][BB][HP]; // double-buffered hidden state

    const int tid = threadIdx.x;

    // --- stage w_hh into LDS ---
    for (int idx = tid; idx < G4 * Hn; idx += 256) {
        int r = idx / Hn, k = idx - r * Hn;
        w_lds[r][k] = w_hh[idx];
    }
    // --- fold fc0 into w_ih: Wc[136][3] + bias (cheap, once per block) ---
    for (int r = tid; r < G4; r += 256) {
        float a0 = 0.f, a1 = 0.f, a2 = 0.f, ab = 0.f;
        for (int k = 0; k < Hn; ++k) {
            float w = w_ih[r * Hn + k];
            a0 += w * fc0_w[k * 3 + 0];
            a1 += w * fc0_w[k * 3 + 1];
            a2 += w * fc0_w[k * 3 + 2];
            ab += w * fc0_b[k];
        }
        wc_lds[r][0] = a0; wc_lds[r][1] = a1; wc_lds[r][2] = a2;
        wc_lds[r][3] = ab + b_ih[r] + b_hh[r];
    }
    // --- zero h buffers ---
    for (int idx = tid; idx < 2 * BB * HP; idx += 256)
        ((float*)h_lds)[idx] = 0.f;
    __syncthreads();

    const int lane = tid & 63;
    const int wv   = tid >> 6;      // wave 0..3
    const int bl   = lane & 7;      // local batch 0..7
    const int sub  = lane >> 3;     // 0..7
    // slot = sub + 8*wv: within a wave, j consecutive -> weight-read banks
    // bl*4 tiling + Dj=1 => Daddr=36 floats = 4 banks => 8 subs tile 32 banks: conflict-free
    const int slot = sub + 8 * wv;  // 0..31
    const long long bg = (long long)blockIdx.x * BB + bl;

    const int j0 = slot;                                   // 0..31
    const bool hasx = (slot == 8) | (slot == 16);          // extra cells j=32 (wave1), j=33 (wave2)
    const int j1 = (slot == 8) ? 32 : 33;

    // hoist j0's folded input weights+bias into registers (fixed per thread)
    const float4 q0 = *(const float4*)wc_lds[0 * Hn + j0];
    const float4 q1 = *(const float4*)wc_lds[1 * Hn + j0];
    const float4 q2 = *(const float4*)wc_lds[2 * Hn + j0];
    const float4 q3 = *(const float4*)wc_lds[3 * Hn + j0];

    float c0 = 0.f, c1 = 0.f;

    const float* xb = x + bg * (long long)(Tn * In);
    float x0 = xb[0], x1 = xb[1], x2 = xb[2];

    int cur = 0;
    for (int t = 0; t < Tn; ++t) {
        // prefetch next timestep's x under this step's compute
        float xn0 = 0.f, xn1 = 0.f, xn2 = 0.f;
        if (t + 1 < Tn) {
            const float* xp = xb + (t + 1) * 3;
            xn0 = xp[0]; xn1 = xp[1]; xn2 = xp[2];
        }

        // h_old for this lane's batch -> registers (8 unique b128 rows, conflict-free)
        float hreg[Hn];
        #pragma unroll
        for (int k = 0; k < Hn; ++k) hreg[k] = h_lds[cur][bl][k];

        const int nxt = cur ^ 1;

        h_lds[nxt][bl][j0] = cellc(j0, hreg, w_lds, q0, q1, q2, q3, x0, x1, x2, c0);
        if (hasx) {
            const float4 p0 = *(const float4*)wc_lds[0 * Hn + j1];
            const float4 p1 = *(const float4*)wc_lds[1 * Hn + j1];
            const float4 p2 = *(const float4*)wc_lds[2 * Hn + j1];
            const float4 p3 = *(const float4*)wc_lds[3 * Hn + j1];
            h_lds[nxt][bl][j1] = cellc(j1, hreg, w_lds, p0, p1, p2, p3, x0, x1, x2, c1);
        }

        __syncthreads();   // h_new complete

        // output flush: 8 batches x 17 float2 = 136 jobs
        float* outb = out + (long long)blockIdx.x * BB * (Tn * Hn) + (long long)t * Hn;
        if (tid < BB * 17) {
            int b = tid / 17;
            int cc = tid - b * 17;
            float2 v;
            v.x = h_lds[nxt][b][2 * cc];
            v.y = h_lds[nxt][b][2 * cc + 1];
            *(float2*)(outb + (long long)b * (Tn * Hn) + 2 * cc) = v;
        }

        cur = nxt;
        x0 = xn0; x1 = xn1; x2 = xn2;
    }
}

} // namespace

extern "C" void kernel_launch(void* const* d_in, const int* in_sizes, int n_in,
                              void* d_out, int out_size, void* d_ws, size_t ws_size,
                              hipStream_t stream) {
    const float* x     = (const float*)d_in[0];
    const float* fc0_w = (const float*)d_in[1];
    const float* fc0_b = (const float*)d_in[2];
    const float* w_ih  = (const float*)d_in[3];
    const float* w_hh  = (const float*)d_in[4];
    const float* b_ih  = (const float*)d_in[5];
    const float* b_hh  = (const float*)d_in[6];
    float* out = (float*)d_out;

    lstm_kernel<<<Bn / BB, 256, 0, stream>>>(x, fc0_w, fc0_b, w_ih, w_hh, b_ih, b_hh, out);
}

// Round 4
// 966.864 us; speedup vs baseline: 1.7753x; 1.1625x over previous
//
#include <hip/hip_runtime.h>

namespace {

constexpr int Bn = 8192;
constexpr int Tn = 365;
constexpr int In = 3;
constexpr int Hn = 34;
constexpr int JJ = 36;     // padded cell count (j=34,35 are zero-cells)
constexpr int BB = 7;      // batches per block
constexpr int NT = BB * JJ; // 252 threads

__device__ __forceinline__ float sigf(float v) { return 1.f / (1.f + __expf(-v)); }
// tanh(x) = 1 - 2/(e^{2x}+1): saturates correctly to +-1 for large |x|
__device__ __forceinline__ float tanhfast(float v) { return 1.f - 2.f / (__expf(2.f * v) + 1.f); }

__global__ __launch_bounds__(NT) void lstm_kernel(
    const float* __restrict__ x,      // [B,T,3]
    const float* __restrict__ fc0_w,  // [34,3]
    const float* __restrict__ fc0_b,  // [34]
    const float* __restrict__ w_ih,   // [136,34]
    const float* __restrict__ w_hh,   // [136,34]
    const float* __restrict__ b_ih,   // [136]
    const float* __restrict__ b_hh,   // [136]
    float* __restrict__ out)          // [B,T,34]
{
    __shared__ float h_lds[2][BB][JJ];   // 2 KB: double-buffered hidden state only

    const int tid = threadIdx.x;         // 0..251
    const int bl  = tid / JJ;            // 0..6
    const int j   = tid - bl * JJ;       // 0..35
    const long long bg = (long long)blockIdx.x * BB + bl;
    const bool bvalid = (bg < Bn);
    const bool jvalid = (j < Hn);
    const bool active = bvalid && jvalid;

    // ---- per-thread weights in REGISTERS (loop-invariant across all 365 steps) ----
    // w[g][k]: recurrent row for gate g of cell j; padded with zeros (k>=34, or j>=34)
    float w[4][JJ];
    float4 q[4];   // folded input-side: xyz = w_ih@fc0_w row, w = folded bias
    #pragma unroll
    for (int g = 0; g < 4; ++g) {
        #pragma unroll
        for (int k = 0; k < JJ; ++k) w[g][k] = 0.f;
        q[g] = make_float4(0.f, 0.f, 0.f, 0.f);
    }
    if (jvalid) {
        #pragma unroll
        for (int g = 0; g < 4; ++g) {
            const int r = g * Hn + j;
            const float* wr = w_hh + (long long)r * Hn;
            #pragma unroll
            for (int k = 0; k < Hn; ++k) w[g][k] = wr[k];
            float a0 = 0.f, a1 = 0.f, a2 = 0.f, ab = 0.f;
            for (int k = 0; k < Hn; ++k) {
                const float wi = w_ih[(long long)r * Hn + k];
                a0 += wi * fc0_w[k * 3 + 0];
                a1 += wi * fc0_w[k * 3 + 1];
                a2 += wi * fc0_w[k * 3 + 2];
                ab += wi * fc0_b[k];
            }
            q[g] = make_float4(a0, a1, a2, ab + b_ih[r] + b_hh[r]);
        }
    }

    // ---- zero h buffers ----
    for (int idx = tid; idx < 2 * BB * JJ; idx += NT)
        ((float*)h_lds)[idx] = 0.f;
    __syncthreads();

    const float* xb = x + (bvalid ? bg : 0) * (long long)(Tn * In);
    float x0 = xb[0], x1 = xb[1], x2 = xb[2];
    float* outp = out + bg * (long long)(Tn * Hn) + j;   // deref only if active

    float c = 0.f;
    int cur = 0;
    for (int t = 0; t < Tn; ++t) {
        // prefetch next step's x under this step's compute
        float xn0 = 0.f, xn1 = 0.f, xn2 = 0.f;
        if (t + 1 < Tn) {
            const float* xp = xb + (t + 1) * 3;
            xn0 = xp[0]; xn1 = xp[1]; xn2 = xp[2];
        }

        // gate pre-activations: folded input side (registers only)
        float a0 = q[0].w + q[0].x * x0 + q[0].y * x1 + q[0].z * x2;
        float a1 = q[1].w + q[1].x * x0 + q[1].y * x1 + q[1].z * x2;
        float a2 = q[2].w + q[2].x * x0 + q[2].y * x1 + q[2].z * x2;
        float a3 = q[3].w + q[3].x * x0 + q[3].y * x1 + q[3].z * x2;

        // recurrent matvec: h from LDS (broadcast reads), weights from registers
        const float* hrow = h_lds[cur][bl];
        #pragma unroll
        for (int kk = 0; kk < JJ / 4; ++kk) {
            const float4 h4 = *(const float4*)(hrow + 4 * kk);
            a0 += w[0][4 * kk + 0] * h4.x; a0 += w[0][4 * kk + 1] * h4.y;
            a0 += w[0][4 * kk + 2] * h4.z; a0 += w[0][4 * kk + 3] * h4.w;
            a1 += w[1][4 * kk + 0] * h4.x; a1 += w[1][4 * kk + 1] * h4.y;
            a1 += w[1][4 * kk + 2] * h4.z; a1 += w[1][4 * kk + 3] * h4.w;
            a2 += w[2][4 * kk + 0] * h4.x; a2 += w[2][4 * kk + 1] * h4.y;
            a2 += w[2][4 * kk + 2] * h4.z; a2 += w[2][4 * kk + 3] * h4.w;
            a3 += w[3][4 * kk + 0] * h4.x; a3 += w[3][4 * kk + 1] * h4.y;
            a3 += w[3][4 * kk + 2] * h4.z; a3 += w[3][4 * kk + 3] * h4.w;
        }

        const float ig = sigf(a0);
        const float fg = sigf(a1);
        const float gg = tanhfast(a2);
        const float og = sigf(a3);
        c = fg * c + ig * gg;
        float hv = og * tanhfast(c);
        if (!jvalid) hv = 0.f;              // keep padding cells exactly zero

        h_lds[cur ^ 1][bl][j] = hv;          // ds_write: addr == tid*4, conflict-free
        if (active) outp[(long long)t * Hn] = hv;  // coalesced-ish across j

        __syncthreads();                     // h_new complete before next step reads it

        cur ^= 1;
        x0 = xn0; x1 = xn1; x2 = xn2;
    }
}

} // namespace

extern "C" void kernel_launch(void* const* d_in, const int* in_sizes, int n_in,
                              void* d_out, int out_size, void* d_ws, size_t ws_size,
                              hipStream_t stream) {
    const float* x     = (const float*)d_in[0];
    const float* fc0_w = (const float*)d_in[1];
    const float* fc0_b = (const float*)d_in[2];
    const float* w_ih  = (const float*)d_in[3];
    const float* w_hh  = (const float*)d_in[4];
    const float* b_ih  = (const float*)d_in[5];
    const float* b_hh  = (const float*)d_in[6];
    float* out = (float*)d_out;

    const int grid = (Bn + BB - 1) / BB;   // 1171
    lstm_kernel<<<grid, NT, 0, stream>>>(x, fc0_w, fc0_b, w_ih, w_hh, b_ih, b_hh, out);
}

// Round 6
// 617.054 us; speedup vs baseline: 2.7818x; 1.5669x over previous
//
#include <hip/hip_runtime.h>

namespace {

constexpr int Bn = 8192;
constexpr int Tn = 365;
constexpr int Hn = 34;
constexpr int GB = 32;     // batches per block = MFMA M
constexpr int KP = 80;     // A row length in shorts (160 B, 16B-aligned); K = 5 chunks of 16
constexpr int JP = 37;     // glds row stride (floats)

typedef __attribute__((ext_vector_type(8))) short bf16x8;    // 8 bf16 = 4 VGPR
typedef __attribute__((ext_vector_type(16))) float f32x16;   // MFMA 32x32 acc

__device__ __forceinline__ unsigned short f2bf(float f) {    // RNE f32->bf16
    union { float f; unsigned u; } v; v.f = f;
    unsigned r = v.u + 0x7fffu + ((v.u >> 16) & 1u);
    return (unsigned short)(r >> 16);
}
__device__ __forceinline__ float bf2f(unsigned short s) {
    union { unsigned u; float f; } v; v.u = ((unsigned)s) << 16; return v.f;
}
__device__ __forceinline__ float sigf(float v) { return 1.f / (1.f + __expf(-v)); }
__device__ __forceinline__ float tanhfast(float v) { return 1.f - 2.f / (__expf(2.f * v) + 1.f); }

// B-operand value W'[r][k]:
//   k 0-33  : bf16(w_hh[r][k])      -- pairs with h_h
//   k 34-67 : bf16(w_hh[r][k-34])   -- pairs with h_l (h residual)
//   k 68-70 : bf16(Wc[r][k-68])     -- pairs with x_h
//   k 71-73 : bf16(Wc[r][k-71])     -- pairs with x_l
//   k 74-76 : Wc - bf2f(bf16(Wc))   -- pairs with x_h (weight residual)
//   else 0
__device__ __forceinline__ bf16x8 build_frag(const float* __restrict__ w_hh,
                                             const float wcv[3], int r, int ks, int hi) {
    bf16x8 f;
    #pragma unroll
    for (int e = 0; e < 8; ++e) {
        int k = 16 * ks + 8 * hi + e;
        float val = 0.f;
        if (r >= 0) {
            if (k < 34)      val = w_hh[r * Hn + k];
            else if (k < 68) val = w_hh[r * Hn + (k - 34)];
            else if (k < 71) val = wcv[k - 68];
            else if (k < 74) val = wcv[k - 71];
            else if (k < 77) { float w = wcv[k - 74]; val = w - bf2f(f2bf(w)); }
        }
        f[e] = (short)f2bf(val);
    }
    return f;
}

__global__ __launch_bounds__(256) void lstm_kernel(
    const float* __restrict__ x,      // [B,T,3]
    const float* __restrict__ fc0_w,  // [34,3]
    const float* __restrict__ fc0_b,  // [34]
    const float* __restrict__ w_ih,   // [136,34]
    const float* __restrict__ w_hh,   // [136,34]
    const float* __restrict__ b_ih,   // [136]
    const float* __restrict__ b_hh,   // [136]
    float* __restrict__ out)          // [B,T,34]
{
    __shared__ unsigned short a_lds[2][GB][KP]; // A operand (bf16): h_h | h_l | x slots
    __shared__ float glds[4][GB][JP];           // gate exchange: [gate][batch][cell]

    const int tid  = threadIdx.x;
    const int lane = tid & 63;
    const int wv   = tid >> 6;      // wave 0..3 -> gate tile wv
    const int n    = lane & 31;     // MFMA col
    const int hi   = lane >> 5;     // k-half selector

    // ---- one-time: fold fc0 into w_ih, build per-lane B-fragments + bias ----
    const int r_m = wv * Hn + n;                                   // gate wv, cell n
    const int r_4 = (wv == 1 && n < 8) ? ((n & 3) * Hn + 32 + (n >> 2)) : -1;

    float wcm[3] = {0.f, 0.f, 0.f};
    float bcm;
    {
        float ab = 0.f;
        for (int m = 0; m < Hn; ++m) {
            float wi = w_ih[r_m * Hn + m];
            wcm[0] += wi * fc0_w[m * 3 + 0];
            wcm[1] += wi * fc0_w[m * 3 + 1];
            wcm[2] += wi * fc0_w[m * 3 + 2];
            ab     += wi * fc0_b[m];
        }
        bcm = ab + b_ih[r_m] + b_hh[r_m];
    }
    bf16x8 Bm[5];
    #pragma unroll
    for (int ks = 0; ks < 5; ++ks) Bm[ks] = build_frag(w_hh, wcm, r_m, ks, hi);

    float wc4[3] = {0.f, 0.f, 0.f};
    float bc4 = 0.f;
    bf16x8 B4[5];
    #pragma unroll
    for (int ks = 0; ks < 5; ++ks) B4[ks] = bf16x8{};
    if (wv == 1) {
        if (r_4 >= 0) {
            float ab = 0.f;
            for (int m = 0; m < Hn; ++m) {
                float wi = w_ih[r_4 * Hn + m];
                wc4[0] += wi * fc0_w[m * 3 + 0];
                wc4[1] += wi * fc0_w[m * 3 + 1];
                wc4[2] += wi * fc0_w[m * 3 + 2];
                ab     += wi * fc0_b[m];
            }
            bc4 = ab + b_ih[r_4] + b_hh[r_4];
        }
        #pragma unroll
        for (int ks = 0; ks < 5; ++ks) B4[ks] = build_frag(w_hh, wc4, r_4, ks, hi);
    }

    // ---- zero A buffers, THEN barrier, THEN write x(t=0)  (R5 bug: this raced) ----
    for (int i = tid; i < 2 * GB * KP; i += 256) ((unsigned short*)a_lds)[i] = 0;
    __syncthreads();

    const long long bg = (long long)blockIdx.x * GB;
    const float* xblk = x + bg * (long long)(Tn * 3);
    float* oblk = out + bg * (long long)(Tn * Hn);

    if (tid < 96) {
        int b = tid / 3, i = tid - b * 3;
        float xr = xblk[b * (Tn * 3) + i];
        unsigned short xh = f2bf(xr);
        unsigned short xl = f2bf(xr - bf2f(xh));
        a_lds[0][b][68 + i] = xh;
        a_lds[0][b][71 + i] = xl;
        a_lds[0][b][74 + i] = xh;
    }
    __syncthreads();

    float cst[5] = {0.f, 0.f, 0.f, 0.f, 0.f};   // cell state (static-indexed)

    for (int t = 0; t < Tn; ++t) {
        const int cur = t & 1, nxt = cur ^ 1;

        // A fragments: lane's batch row = n; chunk ks covers k = 16*ks + 8*hi + e
        const unsigned short* arow = &a_lds[cur][n][0];
        bf16x8 av[5];
        #pragma unroll
        for (int ks = 0; ks < 5; ++ks)
            av[ks] = *(const bf16x8*)(arow + 16 * ks + 8 * hi);

        // prefetch next step's x under this step's compute
        float xr = 0.f;
        if (tid < 96 && t + 1 < Tn) {
            int b = tid / 3, i = tid - b * 3;
            xr = xblk[b * (Tn * 3) + (t + 1) * 3 + i];
        }

        // main tile: D = A*B + bias
        f32x16 acc;
        #pragma unroll
        for (int r = 0; r < 16; ++r) acc[r] = bcm;
        #pragma unroll
        for (int ks = 0; ks < 5; ++ks)
            acc = __builtin_amdgcn_mfma_f32_32x32x16_bf16(av[ks], Bm[ks], acc, 0, 0, 0);

        // wave-uniform nonlinearity (tile 2 = g-gate -> tanh, else sigmoid)
        if (wv == 2) {
            #pragma unroll
            for (int r = 0; r < 16; ++r) acc[r] = tanhfast(acc[r]);
        } else {
            #pragma unroll
            for (int r = 0; r < 16; ++r) acc[r] = sigf(acc[r]);
        }
        // write gates: C/D row rr = (r&3)+8*(r>>2)+4*hi, col n
        #pragma unroll
        for (int r = 0; r < 16; ++r) {
            int rr = (r & 3) + 8 * (r >> 2) + 4 * hi;
            glds[wv][rr][n] = acc[r];
        }
        // tile 4 (wave 1): raw pre-acts for cells 32,33 (cols 0..7)
        if (wv == 1) {
            f32x16 a4;
            #pragma unroll
            for (int r = 0; r < 16; ++r) a4[r] = bc4;
            #pragma unroll
            for (int ks = 0; ks < 5; ++ks)
                a4 = __builtin_amdgcn_mfma_f32_32x32x16_bf16(av[ks], B4[ks], a4, 0, 0, 0);
            if (n < 8) {
                #pragma unroll
                for (int r = 0; r < 16; ++r) {
                    int rr = (r & 3) + 8 * (r >> 2) + 4 * hi;
                    glds[n & 3][rr][32 + (n >> 2)] = a4[r];
                }
            }
        }
        __syncthreads();

        // ---- update phase: 256 threads x 4 cells (+ cells 32/33 on wave 0) ----
        #pragma unroll
        for (int p = 0; p < 4; ++p) {
            int v = p * 256 + tid;
            int b = v >> 5;          // 0..31
            int j = v & 31;          // 0..31
            float gi = glds[0][b][j];
            float gf = glds[1][b][j];
            float gg = glds[2][b][j];
            float go = glds[3][b][j];
            cst[p] = gf * cst[p] + gi * gg;
            float h = go * tanhfast(cst[p]);
            oblk[(long long)b * (Tn * Hn) + t * Hn + j] = h;    // coalesced 32-lane runs
            unsigned short hh = f2bf(h);
            a_lds[nxt][b][j]      = hh;                  // h_h
            a_lds[nxt][b][34 + j] = f2bf(h - bf2f(hh));  // h_l residual
        }
        if (tid < 64) {              // cells 32,33: raw pre-acts -> nonlin here
            int b = tid & 31, j = 32 + (tid >> 5);
            float gi = sigf(glds[0][b][j]);
            float gf = sigf(glds[1][b][j]);
            float gg = tanhfast(glds[2][b][j]);
            float go = sigf(glds[3][b][j]);
            cst[4] = gf * cst[4] + gi * gg;
            float h = go * tanhfast(cst[4]);
            oblk[(long long)b * (Tn * Hn) + t * Hn + j] = h;
            unsigned short hh = f2bf(h);
            a_lds[nxt][b][j]      = hh;
            a_lds[nxt][b][34 + j] = f2bf(h - bf2f(hh));
        }
        if (tid < 96) {              // stage x(t+1) hi/lo into next A buffer
            int b = tid / 3, i = tid - (tid / 3) * 3;
            unsigned short xh = f2bf(xr);
            unsigned short xl = f2bf(xr - bf2f(xh));
            a_lds[nxt][b][68 + i] = xh;
            a_lds[nxt][b][71 + i] = xl;
            a_lds[nxt][b][74 + i] = xh;
        }
        __syncthreads();
    }
}

} // namespace

extern "C" void kernel_launch(void* const* d_in, const int* in_sizes, int n_in,
                              void* d_out, int out_size, void* d_ws, size_t ws_size,
                              hipStream_t stream) {
    const float* x     = (const float*)d_in[0];
    const float* fc0_w = (const float*)d_in[1];
    const float* fc0_b = (const float*)d_in[2];
    const float* w_ih  = (const float*)d_in[3];
    const float* w_hh  = (const float*)d_in[4];
    const float* b_ih  = (const float*)d_in[5];
    const float* b_hh  = (const float*)d_in[6];
    float* out = (float*)d_out;

    lstm_kernel<<<Bn / GB, 256, 0, stream>>>(x, fc0_w, fc0_b, w_ih, w_hh, b_ih, b_hh, out);
}

// Round 7
// 557.691 us; speedup vs baseline: 3.0779x; 1.1064x over previous
//
#include <hip/hip_runtime.h>

namespace {

constexpr int Bn = 8192;
constexpr int Tn = 365;
constexpr int Hn = 34;
constexpr int GB = 16;     // batches per block = MFMA M  -> grid 512, 2 blocks/CU
constexpr int KP = 104;    // A row stride in shorts (208 B = 52 words; 2-way banks)
constexpr int JP = 35;     // glds row stride in floats (odd -> conflict-free)

typedef __attribute__((ext_vector_type(8))) short bf16x8;   // 8 bf16 = 4 VGPR
typedef __attribute__((ext_vector_type(4))) float f32x4;    // 16x16 MFMA acc

__device__ __forceinline__ unsigned short f2bf(float f) {   // RNE f32->bf16
    union { float f; unsigned u; } v; v.f = f;
    unsigned r = v.u + 0x7fffu + ((v.u >> 16) & 1u);
    return (unsigned short)(r >> 16);
}
__device__ __forceinline__ float bf2f(unsigned short s) {
    union { unsigned u; float f; } v; v.u = ((unsigned)s) << 16; return v.f;
}
__device__ __forceinline__ float sigf(float v) { return 1.f / (1.f + __expf(-v)); }
__device__ __forceinline__ float tanhfast(float v) { return 1.f - 2.f / (__expf(2.f * v) + 1.f); }

// pack h into hi/lo bf16 pair (u32: low short = h_h, high short = h_l)
__device__ __forceinline__ unsigned packh(float h) {
    unsigned short hh = f2bf(h);
    unsigned short hl = f2bf(h - bf2f(hh));
    return (unsigned)hh | ((unsigned)hl << 16);
}

// K-layout (77 used, padded to 96/104):
//   k = 2j   : h_h[j]  <-> bf16(w_hh[r][j])
//   k = 2j+1 : h_l[j]  <-> bf16(w_hh[r][j])   (W_h*(h_h+h_l) = W_h*h exactly)
//   k 68-70  : x_h[i]  <-> bf16(Wc[r][i])
//   k 71-73  : x_l[i]  <-> bf16(Wc[r][i])
//   k 74-76  : x_h[i]  <-> bf16(Wc - bf2f(bf16(Wc)))  (weight residual)

__global__ __launch_bounds__(256) void lstm_kernel(
    const float* __restrict__ x,      // [B,T,3]
    const float* __restrict__ fc0_w,  // [34,3]
    const float* __restrict__ fc0_b,  // [34]
    const float* __restrict__ w_ih,   // [136,34]
    const float* __restrict__ w_hh,   // [136,34]
    const float* __restrict__ b_ih,   // [136]
    const float* __restrict__ b_hh,   // [136]
    float* __restrict__ out)          // [B,T,34]
{
    __shared__ unsigned short a_lds[2][GB][KP]; // A operand (bf16), double-buffered
    __shared__ float glds[4][GB][JP];           // gate exchange: [gate][batch][cell]

    const int tid  = threadIdx.x;
    const int lane = tid & 63;
    const int wv   = tid >> 6;      // wave = gate tile g
    const int col  = lane & 15;     // MFMA col (cell) / A row (batch)
    const int kg   = lane >> 4;     // k-group: k = kg*8 + e within a 32-k chunk

    // ---- one-time: per-lane B-fragments (3 N-tiles x 3 K-chunks) + biases ----
    bf16x8 Bt[3][3];
    float bc[3];
    #pragma unroll
    for (int n = 0; n < 3; ++n) {
        const int cell = n * 16 + col;
        const int r = (cell < Hn) ? wv * Hn + cell : -1;
        float wcv[3] = {0.f, 0.f, 0.f};
        float bb = 0.f;
        if (r >= 0) {
            float ab = 0.f;
            for (int m = 0; m < Hn; ++m) {
                const float wi = w_ih[r * Hn + m];
                wcv[0] += wi * fc0_w[m * 3 + 0];
                wcv[1] += wi * fc0_w[m * 3 + 1];
                wcv[2] += wi * fc0_w[m * 3 + 2];
                ab     += wi * fc0_b[m];
            }
            bb = ab + b_ih[r] + b_hh[r];
        }
        bc[n] = bb;
        #pragma unroll
        for (int ks = 0; ks < 3; ++ks) {
            bf16x8 f;
            #pragma unroll
            for (int e = 0; e < 8; ++e) {
                const int k = ks * 32 + kg * 8 + e;
                float val = 0.f;
                if (r >= 0) {
                    if (k < 68)      val = w_hh[r * Hn + (k >> 1)];
                    else if (k < 71) val = wcv[k - 68];
                    else if (k < 74) val = wcv[k - 71];
                    else if (k < 77) { const float w = wcv[k - 74]; val = w - bf2f(f2bf(w)); }
                }
                f[e] = (short)f2bf(val);
            }
            Bt[n][ks] = f;
        }
    }

    // ---- update-phase cell assignment: v = tid, tid+256, (tid<32) 512+tid ----
    const int v0 = tid,        b0 = v0 / Hn, j0 = v0 - b0 * Hn;
    const int v1 = tid + 256,  b1 = v1 / Hn, j1 = v1 - b1 * Hn;
    const int v2 = tid + 512,  b2 = v2 / Hn, j2 = v2 - b2 * Hn;  // valid tid<32
    float c0 = 0.f, c1 = 0.f, c2 = 0.f;

    // x staging assignment (16 batches x 3 features = 48 threads)
    const int bx = tid / 3, ix = tid - bx * 3;

    // ---- zero A buffers; barrier; write x(t=0) (ordering bug of R5 fixed) ----
    for (int i = tid; i < 2 * GB * KP; i += 256) ((unsigned short*)a_lds)[i] = 0;
    __syncthreads();

    const long long bg = (long long)blockIdx.x * GB;
    const float* xblk = x + bg * (long long)(Tn * 3);
    float* oblk = out + bg * (long long)(Tn * Hn);

    if (tid < 48) {
        const float xr = xblk[bx * (Tn * 3) + ix];
        const unsigned short xh = f2bf(xr);
        a_lds[0][bx][68 + ix] = xh;
        a_lds[0][bx][71 + ix] = f2bf(xr - bf2f(xh));
        a_lds[0][bx][74 + ix] = xh;
    }
    __syncthreads();

    for (int t = 0; t < Tn; ++t) {
        const int cur = t & 1, nxt = cur ^ 1;

        // A fragments: row = col(batch), chunk ks at shorts offset ks*32 + kg*8
        bf16x8 av[3];
        #pragma unroll
        for (int ks = 0; ks < 3; ++ks)
            av[ks] = *(const bf16x8*)(&a_lds[cur][col][ks * 32 + kg * 8]);

        // prefetch next step's x under this step's compute
        float xr = 0.f;
        if (tid < 48 && t + 1 < Tn)
            xr = xblk[bx * (Tn * 3) + (t + 1) * 3 + ix];

        // 3 N-tiles: D = A*B + bias
        f32x4 acc[3];
        #pragma unroll
        for (int n = 0; n < 3; ++n) {
            acc[n] = f32x4{bc[n], bc[n], bc[n], bc[n]};
            #pragma unroll
            for (int ks = 0; ks < 3; ++ks)
                acc[n] = __builtin_amdgcn_mfma_f32_16x16x32_bf16(av[ks], Bt[n][ks], acc[n], 0, 0, 0);
        }

        // wave-uniform nonlinearity (gate 2 -> tanh, else sigmoid)
        if (wv == 2) {
            #pragma unroll
            for (int n = 0; n < 3; ++n)
                #pragma unroll
                for (int p = 0; p < 4; ++p) acc[n][p] = tanhfast(acc[n][p]);
        } else {
            #pragma unroll
            for (int n = 0; n < 3; ++n)
                #pragma unroll
                for (int p = 0; p < 4; ++p) acc[n][p] = sigf(acc[n][p]);
        }

        // write gates: C/D row (batch) = kg*4+p, col (cell) = n*16+col
        #pragma unroll
        for (int n = 0; n < 3; ++n) {
            const int j = n * 16 + col;
            if (j < Hn) {
                #pragma unroll
                for (int p = 0; p < 4; ++p)
                    glds[wv][kg * 4 + p][j] = acc[n][p];
            }
        }
        __syncthreads();

        // ---- update phase: 544 cells over 256 threads (2 + tid<32 extra) ----
        {
            const float gi = glds[0][b0][j0], gf = glds[1][b0][j0];
            const float gg = glds[2][b0][j0], go = glds[3][b0][j0];
            c0 = gf * c0 + gi * gg;
            const float h = go * tanhfast(c0);
            oblk[(long long)b0 * (Tn * Hn) + t * Hn + j0] = h;
            ((unsigned*)&a_lds[nxt][b0][0])[j0] = packh(h);
        }
        {
            const float gi = glds[0][b1][j1], gf = glds[1][b1][j1];
            const float gg = glds[2][b1][j1], go = glds[3][b1][j1];
            c1 = gf * c1 + gi * gg;
            const float h = go * tanhfast(c1);
            oblk[(long long)b1 * (Tn * Hn) + t * Hn + j1] = h;
            ((unsigned*)&a_lds[nxt][b1][0])[j1] = packh(h);
        }
        if (tid < 32) {
            const float gi = glds[0][b2][j2], gf = glds[1][b2][j2];
            const float gg = glds[2][b2][j2], go = glds[3][b2][j2];
            c2 = gf * c2 + gi * gg;
            const float h = go * tanhfast(c2);
            oblk[(long long)b2 * (Tn * Hn) + t * Hn + j2] = h;
            ((unsigned*)&a_lds[nxt][b2][0])[j2] = packh(h);
        }
        if (tid < 48) {   // stage x(t+1) into next A buffer
            const unsigned short xh = f2bf(xr);
            a_lds[nxt][bx][68 + ix] = xh;
            a_lds[nxt][bx][71 + ix] = f2bf(xr - bf2f(xh));
            a_lds[nxt][bx][74 + ix] = xh;
        }
        __syncthreads();
    }
}

} // namespace

extern "C" void kernel_launch(void* const* d_in, const int* in_sizes, int n_in,
                              void* d_out, int out_size, void* d_ws, size_t ws_size,
                              hipStream_t stream) {
    const float* x     = (const float*)d_in[0];
    const float* fc0_w = (const float*)d_in[1];
    const float* fc0_b = (const float*)d_in[2];
    const float* w_ih  = (const float*)d_in[3];
    const float* w_hh  = (const float*)d_in[4];
    const float* b_ih  = (const float*)d_in[5];
    const float* b_hh  = (const float*)d_in[6];
    float* out = (float*)d_out;

    lstm_kernel<<<Bn / GB, 256, 0, stream>>>(x, fc0_w, fc0_b, w_ih, w_hh, b_ih, b_hh, out);
}

// Round 9
// 413.658 us; speedup vs baseline: 4.1496x; 1.3482x over previous
//
#include <hip/hip_runtime.h>

namespace {

constexpr int Bn = 8192;
constexpr int Tn = 365;
constexpr int Hn = 34;
constexpr int GB = 16;      // batches per block -> grid 512, 2 blocks/CU
constexpr int KP = 104;     // a_lds row stride in shorts (208 B = 52 words; 2-way banks)
constexpr int GS = 44;      // g_lds row stride in floats (176 B; 2-way banks for b128)

constexpr float LOG2E = 1.44269504088896340736f;

typedef __attribute__((ext_vector_type(8))) short bf16x8;   // 8 bf16 = 4 VGPR
typedef __attribute__((ext_vector_type(4))) float f32x4;    // 16x16 MFMA acc

__device__ __forceinline__ float fexp2(float v) { return __builtin_amdgcn_exp2f(v); }
__device__ __forceinline__ float frcp(float v)  { return __builtin_amdgcn_rcpf(v); }

__device__ __forceinline__ unsigned short f2bf(float f) {   // RNE f32->bf16
    union { float f; unsigned u; } v; v.f = f;
    unsigned r = v.u + 0x7fffu + ((v.u >> 16) & 1u);
    return (unsigned short)(r >> 16);
}
__device__ __forceinline__ float bf2f(unsigned short s) {
    union { unsigned u; float f; } v; v.u = ((unsigned)s) << 16; return v.f;
}
// pack h into hi/lo bf16 pair (low short = h_h at even k, high short = h_l)
__device__ __forceinline__ unsigned packh(float h) {
    unsigned short hh = f2bf(h);
    unsigned short hl = f2bf(h - bf2f(hh));
    return (unsigned)hh | ((unsigned)hl << 16);
}

// K-layout (77 used of 96; pads stay zero):
//   k = 2j   : h_h[j] <-> bf16(w_hh[r][j])
//   k = 2j+1 : h_l[j] <-> bf16(w_hh[r][j])
//   k 68-70  : x_h[i] <-> bf16(Wc[r][i])
//   k 71-73  : x_l[i] <-> bf16(Wc[r][i])
//   k 74-76  : x_h[i] <-> bf16(Wc - bf2f(bf16(Wc)))

__global__ __launch_bounds__(256) void lstm_kernel(
    const float* __restrict__ x,      // [B,T,3]
    const float* __restrict__ fc0_w,  // [34,3]
    const float* __restrict__ fc0_b,  // [34]
    const float* __restrict__ w_ih,   // [136,34]
    const float* __restrict__ w_hh,   // [136,34]
    const float* __restrict__ b_ih,   // [136]
    const float* __restrict__ b_hh,   // [136]
    float* __restrict__ out)          // [B,T,34]
{
    __shared__ __align__(16) unsigned short a_lds[2][GB][KP]; // A operand, double-buffered
    __shared__ __align__(16) float g_lds[4][GB][GS];          // per-WAVE gate slice [wv][b][rhat]

    const int tid  = threadIdx.x;
    const int lane = tid & 63;
    const int wv   = tid >> 6;      // wave id
    const int c    = lane & 15;     // MFMA col (N-row rhat within tile) / A-row (batch)
    const int kg   = lane >> 4;     // k-group / C-row group

    // cell partition across waves: {9,9,8,8}
    const int nc   = (wv < 2) ? 9 : 8;
    const int base = (wv < 2) ? 9 * wv : 18 + 8 * (wv - 2);

    // ---- one-time: B-fragments (3 N-tiles x 3 K-chunks) + biases ----
    // N-packing: rhat = 4*jl + g  (jl = local cell, g = gate i,f,g,o)
    bf16x8 Bt[3][3];
    float bc[3];
    #pragma unroll
    for (int tau = 0; tau < 3; ++tau) {
        const int rhat = 16 * tau + c;
        const int jl = rhat >> 2, g = rhat & 3;
        const int r = (rhat < 4 * nc) ? g * Hn + (base + jl) : -1;
        float wcv[3] = {0.f, 0.f, 0.f};
        float bb = 0.f;
        if (r >= 0) {
            float ab = 0.f;
            for (int m = 0; m < Hn; ++m) {
                const float wi = w_ih[r * Hn + m];
                wcv[0] += wi * fc0_w[m * 3 + 0];
                wcv[1] += wi * fc0_w[m * 3 + 1];
                wcv[2] += wi * fc0_w[m * 3 + 2];
                ab     += wi * fc0_b[m];
            }
            bb = ab + b_ih[r] + b_hh[r];
        }
        bc[tau] = bb;
        #pragma unroll
        for (int ks = 0; ks < 3; ++ks) {
            bf16x8 f;
            #pragma unroll
            for (int e = 0; e < 8; ++e) {
                const int k = ks * 32 + kg * 8 + e;
                float val = 0.f;
                if (r >= 0) {
                    if (k < 68)      val = w_hh[r * Hn + (k >> 1)];
                    else if (k < 71) val = wcv[k - 68];
                    else if (k < 74) val = wcv[k - 71];
                    else if (k < 77) { const float w = wcv[k - 74]; val = w - bf2f(f2bf(w)); }
                }
                f[e] = (short)f2bf(val);
            }
            Bt[tau][ks] = f;
        }
    }

    // per-lane nonlinearity constants: gate = (16*tau+c)&3 = c&3 (tau-independent)
    const bool isg2 = ((c & 3) == 2);                 // g-gate -> tanh
    const float sE = isg2 ? (2.f * LOG2E) : (-LOG2E); // fexp2(v*sE) = exp(2v) or exp(-v)
    const float ku = isg2 ? -2.f : 1.f;               // out = ku*u + kc, u = 1/(1+e)
    const float kc = isg2 ?  1.f : 0.f;

    // update-phase mapping: lane -> batch ub = c, cells jl = {kg, 4+kg, (kg==0 && nc==9) 8}
    const int ub = c;
    const bool has2 = (nc == 9) && (kg == 0);
    float c0 = 0.f, c1 = 0.f, c2 = 0.f;      // cell states
    float h0 = 0.f, h1 = 0.f, h2 = 0.f;      // h kept in regs for next-step store

    // x staging: wave w stages batches 4w..4w+3 (12 lanes x 1 feature)
    const bool xact = (lane < 12);
    const int bx = 4 * wv + lane / 3;
    const int ix = lane - 3 * (lane / 3);

    // ---- zero both A buffers (pads must stay 0); barrier; write x(0) ----
    for (int i = tid; i < 2 * GB * KP; i += 256) ((unsigned short*)a_lds)[i] = 0;
    __syncthreads();

    const long long bg = (long long)blockIdx.x * GB;
    const float* xblk = x + bg * (long long)(Tn * 3);
    float* oblk = out + bg * (long long)(Tn * Hn);
    const long long TH = (long long)Tn * Hn;

    if (xact) {
        const float xr = xblk[bx * (Tn * 3) + ix];
        const unsigned short xh = f2bf(xr);
        a_lds[0][bx][68 + ix] = xh;
        a_lds[0][bx][71 + ix] = f2bf(xr - bf2f(xh));
        a_lds[0][bx][74 + ix] = xh;
    }
    __syncthreads();

    for (int t = 0; t < Tn; ++t) {
        const int cur = t & 1, nxt = cur ^ 1;

        // ---- top of step: issue ALL global ops (retire under this step's compute) ----
        if (t) {   // store h(t-1) from registers
            const long long tb = (long long)ub * TH + (long long)(t - 1) * Hn + base;
            oblk[tb + kg]     = h0;
            oblk[tb + 4 + kg] = h1;
            if (has2) oblk[tb + 8] = h2;
        }
        float xr = 0.f;
        if (xact && t + 1 < Tn)
            xr = xblk[bx * (Tn * 3) + (t + 1) * 3 + ix];

        // ---- A fragments (row = batch = c, chunk ks at shorts ks*32 + kg*8) ----
        bf16x8 av[3];
        #pragma unroll
        for (int ks = 0; ks < 3; ++ks)
            av[ks] = *(const bf16x8*)(&a_lds[cur][c][ks * 32 + kg * 8]);

        // ---- MFMA: gates for this wave's cells, all 16 batches ----
        f32x4 acc[3];
        #pragma unroll
        for (int tau = 0; tau < 3; ++tau) {
            acc[tau] = f32x4{bc[tau], bc[tau], bc[tau], bc[tau]};
            #pragma unroll
            for (int ks = 0; ks < 3; ++ks)
                acc[tau] = __builtin_amdgcn_mfma_f32_16x16x32_bf16(av[ks], Bt[tau][ks], acc[tau], 0, 0, 0);
        }

        // ---- branchless nonlinearity + gate write to wave-private g_lds ----
        // C/D: col = c (rhat), row = 4*kg + p (batch)
        #pragma unroll
        for (int tau = 0; tau < 3; ++tau) {
            #pragma unroll
            for (int p = 0; p < 4; ++p) {
                const float v  = acc[tau][p];
                const float e2 = fexp2(v * sE);
                const float u  = frcp(1.f + e2);
                const float gv = fmaf(ku, u, kc);
                if (16 * tau + c < 4 * nc)
                    g_lds[wv][4 * kg + p][16 * tau + c] = gv;
            }
        }

        // ---- in-wave fence: gate writes -> gate reads (no s_barrier needed) ----
        __builtin_amdgcn_sched_barrier(0);
        asm volatile("s_waitcnt lgkmcnt(0)" ::: "memory");
        __builtin_amdgcn_sched_barrier(0);

        // ---- update: lane = (batch ub, cells kg / 4+kg / 8); gates = one b128 each ----
        {
            const f32x4 gv = *(const f32x4*)&g_lds[wv][ub][4 * kg];
            c0 = gv[1] * c0 + gv[0] * gv[2];
            const float e2 = fexp2(c0 * (2.f * LOG2E));
            const float u  = frcp(1.f + e2);
            h0 = gv[3] * fmaf(-2.f, u, 1.f);
            ((unsigned*)&a_lds[nxt][ub][0])[base + kg] = packh(h0);
        }
        {
            const f32x4 gv = *(const f32x4*)&g_lds[wv][ub][4 * (4 + kg)];
            c1 = gv[1] * c1 + gv[0] * gv[2];
            const float e2 = fexp2(c1 * (2.f * LOG2E));
            const float u  = frcp(1.f + e2);
            h1 = gv[3] * fmaf(-2.f, u, 1.f);
            ((unsigned*)&a_lds[nxt][ub][0])[base + 4 + kg] = packh(h1);
        }
        if (has2) {
            const f32x4 gv = *(const f32x4*)&g_lds[wv][ub][4 * 8];
            c2 = gv[1] * c2 + gv[0] * gv[2];
            const float e2 = fexp2(c2 * (2.f * LOG2E));
            const float u  = frcp(1.f + e2);
            h2 = gv[3] * fmaf(-2.f, u, 1.f);
            ((unsigned*)&a_lds[nxt][ub][0])[base + 8] = packh(h2);
        }

        // ---- stage x(t+1) into next A buffer ----
        if (xact) {
            const unsigned short xh = f2bf(xr);
            a_lds[nxt][bx][68 + ix] = xh;
            a_lds[nxt][bx][71 + ix] = f2bf(xr - bf2f(xh));
            a_lds[nxt][bx][74 + ix] = xh;
        }

        __syncthreads();   // the ONE barrier: h(t) visible to all waves for t+1
    }

    // final store: h(Tn-1)
    {
        const long long tb = (long long)ub * TH + (long long)(Tn - 1) * Hn + base;
        oblk[tb + kg]     = h0;
        oblk[tb + 4 + kg] = h1;
        if (has2) oblk[tb + 8] = h2;
    }
}

} // namespace

extern "C" void kernel_launch(void* const* d_in, const int* in_sizes, int n_in,
                              void* d_out, int out_size, void* d_ws, size_t ws_size,
                              hipStream_t stream) {
    const float* x     = (const float*)d_in[0];
    const float* fc0_w = (const float*)d_in[1];
    const float* fc0_b = (const float*)d_in[2];
    const float* w_ih  = (const float*)d_in[3];
    const float* w_hh  = (const float*)d_in[4];
    const float* b_ih  = (const float*)d_in[5];
    const float* b_hh  = (const float*)d_in[6];
    float* out = (float*)d_out;

    lstm_kernel<<<Bn / GB, 256, 0, stream>>>(x, fc0_w, fc0_b, w_ih, w_hh, b_ih, b_hh, out);
}